// Round 3
// baseline (434.109 us; speedup 1.0000x reference)
//
#include <hip/hip_runtime.h>

#define N_NODES 100000
#define N_EDGES 1600000
#define D_NODE 96
#define D_EDGE 32
#define N_GRAPHS 128
#define BN_EPS 1e-5f

#define EDGE_BLOCKS 6250      // 6250*256 == 1,600,000 == N_EDGES exactly (1 edge/thread)
#define EDGE_THREADS 256
#define PT_STRIDE 6272        // EDGE_BLOCKS padded

// ---------------- prep: fold BN into weights ----------------
// w1n[16][96]  = A[k] * W1[k][0:96]
// w1e[16][32]  = A[k] * W1[k][96:128]
// cw[0:16]  = C[k] = A[k]*(b1[k]-mean[k]) + beta[k]
// cw[16:32] = W2[k]
// cw[32]    = b2
__global__ void prep_kernel(const float* __restrict__ W1, const float* __restrict__ b1,
                            const float* __restrict__ gamma, const float* __restrict__ beta,
                            const float* __restrict__ rmean, const float* __restrict__ rvar,
                            const float* __restrict__ W2, const float* __restrict__ b2,
                            float* __restrict__ w1n, float* __restrict__ w1e,
                            float* __restrict__ cw) {
    int t = threadIdx.x;
    if (t < 16) {
        float A = gamma[t] * rsqrtf(rvar[t] + BN_EPS);
        cw[t] = A * (b1[t] - rmean[t]) + beta[t];
        cw[16 + t] = W2[t];
        for (int j = 0; j < D_NODE; ++j)
            w1n[t * D_NODE + j] = A * W1[t * (D_NODE + D_EDGE) + j];
        for (int j = 0; j < D_EDGE; ++j)
            w1e[t * D_EDGE + j] = A * W1[t * (D_NODE + D_EDGE) + D_NODE + j];
    }
    if (t == 16) cw[32] = b2[0];
}

// ---------------- node projection: y[n][k] = sum_i x[n][i]*w1n[k][i] ----------------
// 4 waves per block, each wave owns a k-quad (q = wave id -> weight addrs wave-uniform -> s_load).
// 64 nodes per block -> 400K threads total (24 waves/CU) instead of 100K (6 waves/CU).
__global__ __launch_bounds__(256) void node_proj_kernel(const float* __restrict__ x,
                                                        const float* __restrict__ w1n,
                                                        float* __restrict__ y) {
    int t = threadIdx.x;
    int q = t >> 6;                        // wave index 0..3 (uniform per wave)
    int n = blockIdx.x * 64 + (t & 63);
    if (n >= N_NODES) return;
    const float4* xr = (const float4*)(x + (size_t)n * D_NODE);
    const float* wq = w1n + (q * 4) * D_NODE;   // wave-uniform base
    float acc[4];
#pragma unroll
    for (int kk = 0; kk < 4; ++kk) acc[kk] = 0.f;
#pragma unroll
    for (int j4 = 0; j4 < D_NODE / 4; ++j4) {
        float4 xv = xr[j4];
#pragma unroll
        for (int kk = 0; kk < 4; ++kk) {
            const float* w = wq + kk * D_NODE + j4 * 4;   // uniform -> s_load
            acc[kk] += xv.x * w[0] + xv.y * w[1] + xv.z * w[2] + xv.w * w[3];
        }
    }
    ((float4*)(y + (size_t)n * 16))[q] = make_float4(acc[0], acc[1], acc[2], acc[3]);
}

// ---------------- edge kernel: 1 edge/thread, acc-resident loop nest ----------------
// i-loop outer / k-loop inner: each ev[i] load is consumed by 16 FMA4s immediately;
// acc[16] stays in VGPRs (no L1 re-reads). Same per-k summation order as before.
__global__ __launch_bounds__(EDGE_THREADS, 8) void edge_kernel(
    const float* __restrict__ ea, const int* __restrict__ eidx,
    const int* __restrict__ batch, const float* __restrict__ y,
    const float* __restrict__ w1e, const float* __restrict__ cw,
    float* __restrict__ partialsT) {
    __shared__ float bins[N_GRAPHS];
    int t = threadIdx.x;
    if (t < N_GRAPHS) bins[t] = 0.f;
    __syncthreads();

    int e = blockIdx.x * EDGE_THREADS + t;
    if (e < N_EDGES) {
        int s = eidx[e];
        int d = eidx[N_EDGES + e];
        int g = batch[d];                      // independent chain, issued early

        float ya[16];
        const float4* yr = (const float4*)(y + (size_t)s * 16);
#pragma unroll
        for (int qq = 0; qq < 4; ++qq) ((float4*)ya)[qq] = yr[qq];

        const float4* er = (const float4*)(ea + (size_t)e * D_EDGE);
        float acc[16];
#pragma unroll
        for (int k = 0; k < 16; ++k) acc[k] = 0.f;
#pragma unroll 2
        for (int i = 0; i < 8; ++i) {
            float4 ev = er[i];
#pragma unroll
            for (int k = 0; k < 16; ++k) {
                const float* w = w1e + k * D_EDGE + i * 4;   // uniform -> s_load
                acc[k] += ev.x * w[0] + ev.y * w[1] + ev.z * w[2] + ev.w * w[3];
            }
        }

        float msg = cw[32];
#pragma unroll
        for (int k = 0; k < 16; ++k) {
            float h = acc[k] + ya[k] + cw[k];
            msg += fmaxf(h, 0.f) * cw[16 + k];
        }
        atomicAdd(&bins[g], msg);
    }

    __syncthreads();
    if (t < N_GRAPHS) partialsT[(size_t)t * PT_STRIDE + blockIdx.x] = bins[t];
}

// ---------------- final reduce: out[g] = sum_b partialsT[g][b] (coalesced reads) ----------------
__global__ __launch_bounds__(256) void reduce_kernel(const float* __restrict__ partialsT,
                                                     float* __restrict__ out) {
    __shared__ float sm[256];
    int g = blockIdx.x;
    float acc = 0.f;
    for (int b = threadIdx.x; b < EDGE_BLOCKS; b += 256)
        acc += partialsT[(size_t)g * PT_STRIDE + b];
    sm[threadIdx.x] = acc;
    __syncthreads();
    for (int w = 128; w > 0; w >>= 1) {
        if (threadIdx.x < w) sm[threadIdx.x] += sm[threadIdx.x + w];
        __syncthreads();
    }
    if (threadIdx.x == 0) out[g] = sm[0];
}

extern "C" void kernel_launch(void* const* d_in, const int* in_sizes, int n_in,
                              void* d_out, int out_size, void* d_ws, size_t ws_size,
                              hipStream_t stream) {
    const float* x     = (const float*)d_in[0];
    const float* ea    = (const float*)d_in[1];
    const int*   eidx  = (const int*)d_in[2];
    const int*   batch = (const int*)d_in[3];
    const float* W1    = (const float*)d_in[4];
    const float* b1    = (const float*)d_in[5];
    const float* gamma = (const float*)d_in[6];
    const float* beta  = (const float*)d_in[7];
    const float* rmean = (const float*)d_in[8];
    const float* rvar  = (const float*)d_in[9];
    const float* W2    = (const float*)d_in[10];
    const float* b2    = (const float*)d_in[11];
    float* out = (float*)d_out;

    float* ws = (float*)d_ws;
    // ws layout (floats):
    float* w1n       = ws;                    // 16*96  = 1536
    float* w1e       = ws + 1536;             // 16*32  = 512
    float* cw        = ws + 2048;             // 33 (pad to 2048)
    float* y         = ws + 4096;             // N_NODES*16 = 1,600,000
    float* partialsT = ws + 4096 + (size_t)N_NODES * 16;  // 128 * PT_STRIDE = 802,816

    prep_kernel<<<1, 64, 0, stream>>>(W1, b1, gamma, beta, rmean, rvar, W2, b2, w1n, w1e, cw);
    node_proj_kernel<<<(N_NODES + 63) / 64, 256, 0, stream>>>(x, w1n, y);
    edge_kernel<<<EDGE_BLOCKS, EDGE_THREADS, 0, stream>>>(ea, eidx, batch, y, w1e, cw, partialsT);
    reduce_kernel<<<N_GRAPHS, 256, 0, stream>>>(partialsT, out);
}

// Round 4
// 413.869 us; speedup vs baseline: 1.0489x; 1.0489x over previous
//
#include <hip/hip_runtime.h>

#define N_NODES 100000
#define N_EDGES 1600000
#define D_NODE 96
#define D_EDGE 32
#define N_GRAPHS 128
#define BN_EPS 1e-5f

#define EDGE_BLOCKS 3125                      // 3125*256*2 == 1,600,000 exactly
#define EDGE_THREADS 256
#define EDGE_STRIDE (EDGE_BLOCKS * EDGE_THREADS)   // 800,000

// ---------------- prep: fold BN into weights ----------------
// w1n[16][96]  = A[k] * W1[k][0:96]
// w1e[16][32]  = A[k] * W1[k][96:128]
// cw[0:16]  = C[k] = A[k]*(b1[k]-mean[k]) + beta[k]
// cw[16:32] = W2[k]
// cw[32]    = b2
__global__ void prep_kernel(const float* __restrict__ W1, const float* __restrict__ b1,
                            const float* __restrict__ gamma, const float* __restrict__ beta,
                            const float* __restrict__ rmean, const float* __restrict__ rvar,
                            const float* __restrict__ W2, const float* __restrict__ b2,
                            float* __restrict__ w1n, float* __restrict__ w1e,
                            float* __restrict__ cw) {
    int t = threadIdx.x;
    if (t < 16) {
        float A = gamma[t] * rsqrtf(rvar[t] + BN_EPS);
        cw[t] = A * (b1[t] - rmean[t]) + beta[t];
        cw[16 + t] = W2[t];
        for (int j = 0; j < D_NODE; ++j)
            w1n[t * D_NODE + j] = A * W1[t * (D_NODE + D_EDGE) + j];
        for (int j = 0; j < D_EDGE; ++j)
            w1e[t * D_EDGE + j] = A * W1[t * (D_NODE + D_EDGE) + D_NODE + j];
    }
    if (t == 16) cw[32] = b2[0];
}

// ---------------- node projection: y[n][k] = sum_i x[n][i]*w1n[k][i] ----------------
// 4 waves per block, each wave owns a k-quad (q = wave id -> weight addrs wave-uniform -> s_load).
__global__ __launch_bounds__(256) void node_proj_kernel(const float* __restrict__ x,
                                                        const float* __restrict__ w1n,
                                                        float* __restrict__ y) {
    int t = threadIdx.x;
    int q = t >> 6;                        // wave index 0..3 (uniform per wave)
    int n = blockIdx.x * 64 + (t & 63);
    if (n >= N_NODES) return;
    const float4* xr = (const float4*)(x + (size_t)n * D_NODE);
    const float* wq = w1n + (q * 4) * D_NODE;   // wave-uniform base
    float acc[4];
#pragma unroll
    for (int kk = 0; kk < 4; ++kk) acc[kk] = 0.f;
#pragma unroll
    for (int j4 = 0; j4 < D_NODE / 4; ++j4) {
        float4 xv = xr[j4];
#pragma unroll
        for (int kk = 0; kk < 4; ++kk) {
            const float* w = wq + kk * D_NODE + j4 * 4;   // uniform -> s_load
            acc[kk] += xv.x * w[0] + xv.y * w[1] + xv.z * w[2] + xv.w * w[3];
        }
    }
    ((float4*)(y + (size_t)n * 16))[q] = make_float4(acc[0], acc[1], acc[2], acc[3]);
}

// ---------------- edge kernel: 2 edges/thread, all loads issued up front ----------------
// ~30 outstanding loads per thread (ea x16, y x8, idx x4, batch x2) then 2x ~1024 cycles
// of pure FMA. Latency is hidden by per-thread ILP, not wave count.
__global__ __launch_bounds__(EDGE_THREADS) void edge_kernel(
    const float* __restrict__ ea, const int* __restrict__ eidx,
    const int* __restrict__ batch, const float* __restrict__ y,
    const float* __restrict__ w1e, const float* __restrict__ cw,
    float* __restrict__ partials) {
    __shared__ float bins[N_GRAPHS];
    int t = threadIdx.x;
    if (t < N_GRAPHS) bins[t] = 0.f;
    __syncthreads();

    int e0 = blockIdx.x * EDGE_THREADS + t;
    int e1 = e0 + EDGE_STRIDE;

    // index chains first (deepest dependency: eidx -> y / batch)
    int s0 = eidx[e0];
    int d0 = eidx[N_EDGES + e0];
    int s1 = eidx[e1];
    int d1 = eidx[N_EDGES + e1];

    const float4* er0 = (const float4*)(ea + (size_t)e0 * D_EDGE);
    const float4* er1 = (const float4*)(ea + (size_t)e1 * D_EDGE);
    float4 eva[8], evb[8];
#pragma unroll
    for (int i = 0; i < 8; ++i) eva[i] = er0[i];
#pragma unroll
    for (int i = 0; i < 8; ++i) evb[i] = er1[i];

    float ya0[16], ya1[16];
    const float4* yr0 = (const float4*)(y + (size_t)s0 * 16);
    const float4* yr1 = (const float4*)(y + (size_t)s1 * 16);
#pragma unroll
    for (int qq = 0; qq < 4; ++qq) ((float4*)ya0)[qq] = yr0[qq];
#pragma unroll
    for (int qq = 0; qq < 4; ++qq) ((float4*)ya1)[qq] = yr1[qq];

    int g0 = batch[d0];
    int g1 = batch[d1];

    float b2v = cw[32];

    // ---- edge 0 ----
    {
        float acc[16];
#pragma unroll
        for (int k = 0; k < 16; ++k) acc[k] = 0.f;
#pragma unroll
        for (int i = 0; i < 8; ++i) {
            float4 ev = eva[i];
#pragma unroll
            for (int k = 0; k < 16; ++k) {
                const float* w = w1e + k * D_EDGE + i * 4;   // uniform -> s_load
                acc[k] += ev.x * w[0] + ev.y * w[1] + ev.z * w[2] + ev.w * w[3];
            }
        }
        float msg = b2v;
#pragma unroll
        for (int k = 0; k < 16; ++k) {
            float h = acc[k] + ya0[k] + cw[k];
            msg += fmaxf(h, 0.f) * cw[16 + k];
        }
        atomicAdd(&bins[g0], msg);
    }

    // ---- edge 1 ----
    {
        float acc[16];
#pragma unroll
        for (int k = 0; k < 16; ++k) acc[k] = 0.f;
#pragma unroll
        for (int i = 0; i < 8; ++i) {
            float4 ev = evb[i];
#pragma unroll
            for (int k = 0; k < 16; ++k) {
                const float* w = w1e + k * D_EDGE + i * 4;   // uniform -> s_load
                acc[k] += ev.x * w[0] + ev.y * w[1] + ev.z * w[2] + ev.w * w[3];
            }
        }
        float msg = b2v;
#pragma unroll
        for (int k = 0; k < 16; ++k) {
            float h = acc[k] + ya1[k] + cw[k];
            msg += fmaxf(h, 0.f) * cw[16 + k];
        }
        atomicAdd(&bins[g1], msg);
    }

    __syncthreads();
    // contiguous per-block row: 512 B coalesced store, no write-allocate churn
    if (t < N_GRAPHS) partials[(size_t)blockIdx.x * N_GRAPHS + t] = bins[t];
}

// ---------------- final reduce: out[g] = sum_b partials[b][g] ----------------
__global__ __launch_bounds__(256) void reduce_kernel(const float* __restrict__ partials,
                                                     float* __restrict__ out) {
    __shared__ float sm[256];
    int g = blockIdx.x;
    float acc = 0.f;
    for (int b = threadIdx.x; b < EDGE_BLOCKS; b += 256)
        acc += partials[(size_t)b * N_GRAPHS + g];
    sm[threadIdx.x] = acc;
    __syncthreads();
    for (int w = 128; w > 0; w >>= 1) {
        if (threadIdx.x < w) sm[threadIdx.x] += sm[threadIdx.x + w];
        __syncthreads();
    }
    if (threadIdx.x == 0) out[g] = sm[0];
}

extern "C" void kernel_launch(void* const* d_in, const int* in_sizes, int n_in,
                              void* d_out, int out_size, void* d_ws, size_t ws_size,
                              hipStream_t stream) {
    const float* x     = (const float*)d_in[0];
    const float* ea    = (const float*)d_in[1];
    const int*   eidx  = (const int*)d_in[2];
    const int*   batch = (const int*)d_in[3];
    const float* W1    = (const float*)d_in[4];
    const float* b1    = (const float*)d_in[5];
    const float* gamma = (const float*)d_in[6];
    const float* beta  = (const float*)d_in[7];
    const float* rmean = (const float*)d_in[8];
    const float* rvar  = (const float*)d_in[9];
    const float* W2    = (const float*)d_in[10];
    const float* b2    = (const float*)d_in[11];
    float* out = (float*)d_out;

    float* ws = (float*)d_ws;
    // ws layout (floats):
    float* w1n      = ws;                    // 16*96  = 1536
    float* w1e      = ws + 1536;             // 16*32  = 512
    float* cw       = ws + 2048;             // 33 (pad to 2048)
    float* y        = ws + 4096;             // N_NODES*16 = 1,600,000
    float* partials = ws + 4096 + (size_t)N_NODES * 16;  // EDGE_BLOCKS*128 = 400,000

    prep_kernel<<<1, 64, 0, stream>>>(W1, b1, gamma, beta, rmean, rvar, W2, b2, w1n, w1e, cw);
    node_proj_kernel<<<(N_NODES + 63) / 64, 256, 0, stream>>>(x, w1n, y);
    edge_kernel<<<EDGE_BLOCKS, EDGE_THREADS, 0, stream>>>(ea, eidx, batch, y, w1e, cw, partials);
    reduce_kernel<<<N_GRAPHS, 256, 0, stream>>>(partials, out);
}

// Round 5
// 413.804 us; speedup vs baseline: 1.0491x; 1.0002x over previous
//
#include <hip/hip_runtime.h>

#define N_NODES 100000
#define N_EDGES 1600000
#define D_NODE 96
#define D_EDGE 32
#define N_GRAPHS 128
#define BN_EPS 1e-5f

#define EDGE_BLOCKS 6250      // 6250*256 == 1,600,000 == N_EDGES exactly (1 edge/thread)
#define EDGE_THREADS 256

typedef float f2 __attribute__((ext_vector_type(2)));

// ---------------- prep: fold BN into weights, TRANSPOSED for packed-k FMA ----------------
// w1nT[96][16] : w1nT[j][k] = A[k] * W1[k][j]        (k-pairs contiguous -> v_pk_fma_f32)
// w1eT[32][16] : w1eT[j][k] = A[k] * W1[k][96+j]
// cw[0:16]  = C[k] = A[k]*(b1[k]-mean[k]) + beta[k]  (k-contiguous -> f2 reinterpret)
// cw[16:32] = W2[k]
// cw[32]    = b2
__global__ void prep_kernel(const float* __restrict__ W1, const float* __restrict__ b1,
                            const float* __restrict__ gamma, const float* __restrict__ beta,
                            const float* __restrict__ rmean, const float* __restrict__ rvar,
                            const float* __restrict__ W2, const float* __restrict__ b2,
                            float* __restrict__ w1nT, float* __restrict__ w1eT,
                            float* __restrict__ cw) {
    int t = threadIdx.x;
    if (t < 16) {
        float A = gamma[t] * rsqrtf(rvar[t] + BN_EPS);
        cw[t] = A * (b1[t] - rmean[t]) + beta[t];
        cw[16 + t] = W2[t];
        for (int j = 0; j < D_NODE; ++j)
            w1nT[j * 16 + t] = A * W1[t * (D_NODE + D_EDGE) + j];
        for (int j = 0; j < D_EDGE; ++j)
            w1eT[j * 16 + t] = A * W1[t * (D_NODE + D_EDGE) + D_NODE + j];
    }
    if (t == 16) cw[32] = b2[0];
}

// ---------------- node projection: y[n][k] = sum_j x[n][j]*w1nT[j][k] ----------------
// 4 waves/block, wave q owns k-quad [4q,4q+4); packed-k FMA (2 f2 accumulators).
__global__ __launch_bounds__(256) void node_proj_kernel(const float* __restrict__ x,
                                                        const float* __restrict__ w1nT,
                                                        float* __restrict__ y) {
    int t = threadIdx.x;
    int q = t >> 6;                          // wave index 0..3 (uniform per wave)
    int n = blockIdx.x * 64 + (t & 63);
    if (n >= N_NODES) return;
    const float4* xr = (const float4*)(x + (size_t)n * D_NODE);
    f2 acc0 = {0.f, 0.f}, acc1 = {0.f, 0.f};
#pragma unroll
    for (int j4 = 0; j4 < D_NODE / 4; ++j4) {
        float4 xv = xr[j4];
#pragma unroll
        for (int u = 0; u < 4; ++u) {
            float xs = (u == 0) ? xv.x : (u == 1) ? xv.y : (u == 2) ? xv.z : xv.w;
            f2 xs2 = {xs, xs};
            const f2* wp = (const f2*)(w1nT + (j4 * 4 + u) * 16 + q * 4);  // uniform -> s_load
            acc0 = __builtin_elementwise_fma(xs2, wp[0], acc0);
            acc1 = __builtin_elementwise_fma(xs2, wp[1], acc1);
        }
    }
    ((float4*)(y + (size_t)n * 16))[q] = make_float4(acc0.x, acc0.y, acc1.x, acc1.y);
}

// ---------------- edge kernel: 1 edge/thread, packed-k inner loop, VGPR<=64 ----------------
__global__ __launch_bounds__(EDGE_THREADS, 8) void edge_kernel(
    const float* __restrict__ ea, const int* __restrict__ eidx,
    const int* __restrict__ batch, const float* __restrict__ y,
    const float* __restrict__ w1eT, const float* __restrict__ cw,
    float* __restrict__ partials) {
    __shared__ float bins[N_GRAPHS];
    int t = threadIdx.x;
    if (t < N_GRAPHS) bins[t] = 0.f;
    __syncthreads();

    int e = blockIdx.x * EDGE_THREADS + t;   // grid covers N_EDGES exactly

    // deepest dependency chains first: eidx -> y gather / batch gather
    int sn = eidx[e];
    int dn = eidx[N_EDGES + e];
    int g  = batch[dn];

    float ya[16];
    const float4* yr = (const float4*)(y + (size_t)sn * 16);
#pragma unroll
    for (int qq = 0; qq < 4; ++qq) ((float4*)ya)[qq] = yr[qq];

    const float4* er = (const float4*)(ea + (size_t)e * D_EDGE);
    float4 ev[8];
#pragma unroll
    for (int i = 0; i < 8; ++i) ev[i] = er[i];

    // acc over k packed in pairs: acc[k2] = (h_{2k2}, h_{2k2+1}) partial sums
    f2 acc[8];
#pragma unroll
    for (int k2 = 0; k2 < 8; ++k2) acc[k2] = (f2){0.f, 0.f};

    const float* evs = (const float*)ev;     // static (unrolled) indexing -> stays in VGPRs
#pragma unroll
    for (int j = 0; j < D_EDGE; ++j) {
        float b = evs[j];
        f2 b2 = {b, b};
        const f2* wp = (const f2*)(w1eT + j * 16);   // uniform -> s_load
#pragma unroll
        for (int k2 = 0; k2 < 8; ++k2)
            acc[k2] = __builtin_elementwise_fma(b2, wp[k2], acc[k2]);
    }

    const f2* ya2 = (const f2*)ya;
    const f2* c2  = (const f2*)cw;           // uniform -> s_load
    const f2* w2p = (const f2*)(cw + 16);
    f2 m2 = {0.f, 0.f};
#pragma unroll
    for (int k2 = 0; k2 < 8; ++k2) {
        f2 h = acc[k2] + ya2[k2] + c2[k2];
        h = __builtin_elementwise_max(h, (f2){0.f, 0.f});
        m2 = __builtin_elementwise_fma(h, w2p[k2], m2);
    }
    float msg = m2.x + m2.y + cw[32];

    atomicAdd(&bins[g], msg);

    __syncthreads();
    // contiguous per-block row: coalesced, no write-allocate churn
    if (t < N_GRAPHS) partials[(size_t)blockIdx.x * N_GRAPHS + t] = bins[t];
}

// ---------------- final reduce: out[g] = sum_b partials[b][g] ----------------
__global__ __launch_bounds__(256) void reduce_kernel(const float* __restrict__ partials,
                                                     float* __restrict__ out) {
    __shared__ float sm[256];
    int g = blockIdx.x;
    float acc = 0.f;
    for (int b = threadIdx.x; b < EDGE_BLOCKS; b += 256)
        acc += partials[(size_t)b * N_GRAPHS + g];
    sm[threadIdx.x] = acc;
    __syncthreads();
    for (int w = 128; w > 0; w >>= 1) {
        if (threadIdx.x < w) sm[threadIdx.x] += sm[threadIdx.x + w];
        __syncthreads();
    }
    if (threadIdx.x == 0) out[g] = sm[0];
}

extern "C" void kernel_launch(void* const* d_in, const int* in_sizes, int n_in,
                              void* d_out, int out_size, void* d_ws, size_t ws_size,
                              hipStream_t stream) {
    const float* x     = (const float*)d_in[0];
    const float* ea    = (const float*)d_in[1];
    const int*   eidx  = (const int*)d_in[2];
    const int*   batch = (const int*)d_in[3];
    const float* W1    = (const float*)d_in[4];
    const float* b1    = (const float*)d_in[5];
    const float* gamma = (const float*)d_in[6];
    const float* beta  = (const float*)d_in[7];
    const float* rmean = (const float*)d_in[8];
    const float* rvar  = (const float*)d_in[9];
    const float* W2    = (const float*)d_in[10];
    const float* b2    = (const float*)d_in[11];
    float* out = (float*)d_out;

    float* ws = (float*)d_ws;
    // ws layout (floats):
    float* w1nT     = ws;                    // 96*16 = 1536
    float* w1eT     = ws + 1536;             // 32*16 = 512
    float* cw       = ws + 2048;             // 33 (pad to 2048)
    float* y        = ws + 4096;             // N_NODES*16 = 1,600,000
    float* partials = ws + 4096 + (size_t)N_NODES * 16;  // EDGE_BLOCKS*128 = 800,000

    prep_kernel<<<1, 64, 0, stream>>>(W1, b1, gamma, beta, rmean, rvar, W2, b2, w1nT, w1eT, cw);
    node_proj_kernel<<<(N_NODES + 63) / 64, 256, 0, stream>>>(x, w1nT, y);
    edge_kernel<<<EDGE_BLOCKS, EDGE_THREADS, 0, stream>>>(ea, eidx, batch, y, w1eT, cw, partials);
    reduce_kernel<<<N_GRAPHS, 256, 0, stream>>>(partials, out);
}